// Round 1
// 966.444 us; speedup vs baseline: 1.0691x; 1.0691x over previous
//
#include <hip/hip_runtime.h>

typedef _Float16 f16;
typedef _Float16 f16x4 __attribute__((ext_vector_type(4)));
typedef _Float16 f16x8 __attribute__((ext_vector_type(8)));
typedef float    f32x4 __attribute__((ext_vector_type(4)));

#define AS1 __attribute__((address_space(1)))
#define AS3 __attribute__((address_space(3)))

__device__ __forceinline__ void gl_lds16(const void* g, void* l) {
  __builtin_amdgcn_global_load_lds((const AS1 void*)g, (AS3 void*)l, 16, 0, 0);
}

#define VMCNT4 asm volatile("s_waitcnt vmcnt(4)" ::: "memory")
#define VMCNT0 asm volatile("s_waitcnt vmcnt(0)" ::: "memory")
#define LGKM0  asm volatile("s_waitcnt lgkmcnt(0)" ::: "memory")
#define BAR()  __builtin_amdgcn_s_barrier()

// ===========================================================================
// OLD 128x128 (m97-structure) kernels — retained for the 128-tile-count
// dispatches (MT, scores, final PV) where 256^2 would leave half the CUs
// idle (predicted neutral there).
// LDS swizzle (verified R4: SQ_LDS_BANK_CONFLICT 4.19M -> 0).
// ===========================================================================
template <int CMODE>
__global__ __launch_bounds__(256) void gemm_nt(
    const f16* __restrict__ A, const f16* __restrict__ B, void* __restrict__ C,
    int K, int lda, int ldb, int ldc, int ZB,
    long sA1, long sA2, long sB1, long sB2, long sC1, long sC2, float scale)
{
  __shared__ __align__(16) f16 As[128 * 32];
  __shared__ __align__(16) f16 Bs[128 * 32];

  const int tid  = threadIdx.x;
  const int wave = tid >> 6;
  const int lane = tid & 63;
  const int quad = lane >> 4;
  const int col  = lane & 15;
  const int wm = (wave & 1) * 64;
  const int wn = (wave >> 1) * 64;

  const int z  = blockIdx.z;
  const int z1 = z % ZB;
  const int z2 = z / ZB;
  const long offA = (long)z1 * sA1 + (long)z2 * sA2;
  const long offB = (long)z1 * sB1 + (long)z2 * sB2;
  const long offC = (long)z1 * sC1 + (long)z2 * sC2;

  const long tile_m = (long)blockIdx.x * 128;
  const long tile_n = (long)blockIdx.y * 128;

  const int rstage = wave * 16 + (lane >> 2);
  const int kq = ((lane & 3) - ((lane >> 3) & 3)) & 3;
  const int kstage = kq * 8;
  const int lstage = (lane & 3) * 8;
  const f16* pa = A + offA + (tile_m + rstage) * (long)lda + kstage;
  const f16* pb = B + offB + (tile_n + rstage) * (long)ldb + kstage;
  f16* la0 = &As[rstage * 32 + lstage];
  f16* la1 = &As[(rstage + 64) * 32 + lstage];
  f16* lb0 = &Bs[rstage * 32 + lstage];
  f16* lb1 = &Bs[(rstage + 64) * 32 + lstage];
  const long skipA = 64L * lda;
  const long skipB = 64L * ldb;

  const int sA_sw = (quad + ((col >> 1) & 3)) & 3;

  f32x4 acc[4][4];
#pragma unroll
  for (int i = 0; i < 4; ++i)
#pragma unroll
    for (int j = 0; j < 4; ++j) acc[i][j] = (f32x4){0.f, 0.f, 0.f, 0.f};

  for (int k0 = 0; k0 < K; k0 += 32) {
    gl_lds16(pa, la0);
    gl_lds16(pa + skipA, la1);
    gl_lds16(pb, lb0);
    gl_lds16(pb + skipB, lb1);
    pa += 32;
    pb += 32;
    __syncthreads();

    const f16x8* A8 = (const f16x8*)As;
    const f16x8* B8 = (const f16x8*)Bs;
    f16x8 af[4], bf[4];
#pragma unroll
    for (int i = 0; i < 4; ++i) af[i] = A8[(wm + i * 16 + col) * 4 + sA_sw];
#pragma unroll
    for (int j = 0; j < 4; ++j) bf[j] = B8[(wn + j * 16 + col) * 4 + sA_sw];
#pragma unroll
    for (int i = 0; i < 4; ++i)
#pragma unroll
      for (int j = 0; j < 4; ++j)
        acc[i][j] = __builtin_amdgcn_mfma_f32_16x16x32_f16(af[i], bf[j], acc[i][j], 0, 0, 0);
    __syncthreads();
  }

  const long cm = tile_m + wm + quad * 4;
  const long cn = tile_n + wn + col;
  if (CMODE == 0) {
    f16* Cp = (f16*)C + offC;
#pragma unroll
    for (int i = 0; i < 4; ++i)
#pragma unroll
      for (int r = 0; r < 4; ++r) {
        const long rowb = (cm + i * 16 + r) * (long)ldc;
#pragma unroll
        for (int j = 0; j < 4; ++j)
          Cp[rowb + cn + j * 16] = (f16)(acc[i][j][r] * scale);
      }
  } else if (CMODE == 1) {
    float* Cp = (float*)C + offC;
#pragma unroll
    for (int i = 0; i < 4; ++i)
#pragma unroll
      for (int r = 0; r < 4; ++r) {
        const long rowb = (cm + i * 16 + r) * (long)ldc;
#pragma unroll
        for (int j = 0; j < 4; ++j)
          Cp[rowb + cn + j * 16] = acc[i][j][r] * scale;
      }
  } else {
    float* Cp = (float*)C + offC;
#pragma unroll
    for (int i = 0; i < 4; ++i)
#pragma unroll
      for (int r = 0; r < 4; ++r) {
        const long rowb = (cm + i * 16 + r) * (long)ldc;
#pragma unroll
        for (int j = 0; j < 4; ++j)
          Cp[rowb + cn + j * 16] += acc[i][j][r] * scale;
      }
  }
}

template <int CMODE>
__global__ __launch_bounds__(256) void gemm_nt3(
    const f16* __restrict__ Ah, const f16* __restrict__ Al,
    const f16* __restrict__ Bh, const f16* __restrict__ Bl,
    void* __restrict__ C, f16* __restrict__ Cl,
    int K, int ldc, int ZB,
    long sA1, long sA2, long sB1, long sB2, long sC1, long sC2, float scale)
{
  __shared__ __align__(16) f16 Ash[128 * 32];
  __shared__ __align__(16) f16 Asl[128 * 32];
  __shared__ __align__(16) f16 Bsh[128 * 32];
  __shared__ __align__(16) f16 Bsl[128 * 32];

  const int tid  = threadIdx.x;
  const int wave = tid >> 6;
  const int lane = tid & 63;
  const int quad = lane >> 4;
  const int col  = lane & 15;
  const int wm = (wave & 1) * 64;
  const int wn = (wave >> 1) * 64;

  const int z  = blockIdx.z;
  const int z1 = z % ZB;
  const int z2 = z / ZB;
  const long offA = (long)z1 * sA1 + (long)z2 * sA2;
  const long offB = (long)z1 * sB1 + (long)z2 * sB2;
  const long offC = (long)z1 * sC1 + (long)z2 * sC2;

  const long tile_m = (long)blockIdx.x * 128;
  const long tile_n = (long)blockIdx.y * 128;

  const int rstage = wave * 16 + (lane >> 2);
  const int kq = ((lane & 3) - ((lane >> 3) & 3)) & 3;
  const int kstage = kq * 8;
  const int lstage = (lane & 3) * 8;
  const long aoff = offA + (tile_m + rstage) * (long)K + kstage;
  const long boff = offB + (tile_n + rstage) * (long)K + kstage;
  const f16* pah = Ah + aoff;
  const f16* pal = Al + aoff;
  const f16* pbh = Bh + boff;
  const f16* pbl = Bl + boff;
  const int lds_o = rstage * 32 + lstage;
  const long skip = 64L * K;

  const int sA_sw = (quad + ((col >> 1) & 3)) & 3;

  f32x4 acc[4][4];
#pragma unroll
  for (int i = 0; i < 4; ++i)
#pragma unroll
    for (int j = 0; j < 4; ++j) acc[i][j] = (f32x4){0.f, 0.f, 0.f, 0.f};

  for (int k0 = 0; k0 < K; k0 += 32) {
    gl_lds16(pah, &Ash[lds_o]);
    gl_lds16(pah + skip, &Ash[lds_o + 64 * 32]);
    gl_lds16(pal, &Asl[lds_o]);
    gl_lds16(pal + skip, &Asl[lds_o + 64 * 32]);
    gl_lds16(pbh, &Bsh[lds_o]);
    gl_lds16(pbh + skip, &Bsh[lds_o + 64 * 32]);
    gl_lds16(pbl, &Bsl[lds_o]);
    gl_lds16(pbl + skip, &Bsl[lds_o + 64 * 32]);
    pah += 32; pal += 32; pbh += 32; pbl += 32;
    __syncthreads();

    const f16x8* A8h = (const f16x8*)Ash;
    const f16x8* A8l = (const f16x8*)Asl;
    const f16x8* B8h = (const f16x8*)Bsh;
    const f16x8* B8l = (const f16x8*)Bsl;
    f16x8 ah[4], al[4], bh[4], bl[4];
#pragma unroll
    for (int i = 0; i < 4; ++i) {
      const int idx = (wm + i * 16 + col) * 4 + sA_sw;
      ah[i] = A8h[idx];
      al[i] = A8l[idx];
    }
#pragma unroll
    for (int j = 0; j < 4; ++j) {
      const int idx = (wn + j * 16 + col) * 4 + sA_sw;
      bh[j] = B8h[idx];
      bl[j] = B8l[idx];
    }
#pragma unroll
    for (int i = 0; i < 4; ++i)
#pragma unroll
      for (int j = 0; j < 4; ++j) {
        acc[i][j] = __builtin_amdgcn_mfma_f32_16x16x32_f16(ah[i], bh[j], acc[i][j], 0, 0, 0);
        acc[i][j] = __builtin_amdgcn_mfma_f32_16x16x32_f16(ah[i], bl[j], acc[i][j], 0, 0, 0);
        acc[i][j] = __builtin_amdgcn_mfma_f32_16x16x32_f16(al[i], bh[j], acc[i][j], 0, 0, 0);
      }
    __syncthreads();
  }

  const long cm = tile_m + wm + quad * 4;
  const long cn = tile_n + wn + col;
  if (CMODE == 0) {
    f16* Ch = (f16*)C + offC;
    f16* Clp = Cl + offC;
#pragma unroll
    for (int i = 0; i < 4; ++i)
#pragma unroll
      for (int r = 0; r < 4; ++r) {
        const long rowb = (cm + i * 16 + r) * (long)ldc;
#pragma unroll
        for (int j = 0; j < 4; ++j) {
          const float v = acc[i][j][r] * scale;
          const f16 hi = (f16)v;
          Ch[rowb + cn + j * 16] = hi;
          Clp[rowb + cn + j * 16] = (f16)(v - (float)hi);
        }
      }
  } else {
    float* Cp = (float*)C + offC;
#pragma unroll
    for (int i = 0; i < 4; ++i)
#pragma unroll
      for (int r = 0; r < 4; ++r) {
        const long rowb = (cm + i * 16 + r) * (long)ldc;
#pragma unroll
        for (int j = 0; j < 4; ++j)
          Cp[rowb + cn + j * 16] = acc[i][j][r] * scale;
      }
  }
}

// ===========================================================================
// NEW 256x256 8-phase cores (T3+T4 counted vmcnt + T5 setprio).
// 512 threads = 8 waves (2M x 4N), per-wave 128x64 output (8x4 frags).
// LDS 128 KiB, strict double-buffer: stages ALWAYS write the other buffer
// (zero region overlap -> race-free by construction). Counted vmcnt(4):
// at each check the 4 newest vm-ops are the only ones allowed outstanding,
// which guarantees exactly the units the next phases read are resident.
// Conflict-free LDS via chunk rotation pos=(chunk+row)&3, realized by
// permuting the per-lane GLOBAL source address (gl_lds dest stays linear,
// m104/m173). Read position = (quad+col)&3 -> 2-way aliasing only (free).
// ===========================================================================

template <int BASE>
__device__ __forceinline__ void mfma4x4(f32x4 (&acc)[8][4],
                                        const f16x8 (&a)[4], const f16x8 (&b)[4]) {
#pragma unroll
  for (int i = 0; i < 4; ++i)
#pragma unroll
    for (int j = 0; j < 4; ++j)
      acc[BASE + i][j] =
          __builtin_amdgcn_mfma_f32_16x16x32_f16(a[i], b[j], acc[BASE + i][j], 0, 0, 0);
}

__device__ __forceinline__ void ld4(f16x8 (&d)[4], const f16* base, int off) {
#pragma unroll
  for (int k = 0; k < 4; ++k) d[k] = *(const f16x8*)(base + off + k * 512);
}

// Plain NT: C = A(MxK) . B(NxK)^T, BK=64, 4 phases/K-tile, 16 MFMA each.
__device__ __forceinline__ void core_plain(
    const f16* __restrict__ pa, const f16* __restrict__ pb,
    int K, int lda, int ldb, f16* As, f16* Bs, f32x4 (&acc)[8][4])
{
  const int tid  = threadIdx.x;
  const int wave = tid >> 6;
  const int lane = tid & 63;
  const int quad = lane >> 4;
  const int col  = lane & 15;
  const int wm = (wave >> 2) * 128;
  const int wn = (wave & 3) * 64;
  const int l_off = wave * 512 + lane * 8;
  const int r0 = wave * 16 + (lane >> 2);
  const int c0 = ((lane & 3) - r0) & 3;
  const long gA  = (long)r0 * lda + c0 * 8;
  const long gA2 = gA + 128L * lda;
  const long gB  = (long)r0 * ldb + c0 * 8;
  const long gB2 = gB + 128L * ldb;
  const int a_off = (wm + col) * 32 + ((quad + col) & 3) * 8;
  const int b_off = (wn + col) * 32 + ((quad + col) & 3) * 8;

  // prologue: tile 0 units U1=A.kk0 U2=B.kk0 U3=A.kk1 U4=B.kk1
  gl_lds16(pa + gA,       As + l_off);
  gl_lds16(pa + gA2,      As + l_off + 4096);
  gl_lds16(pb + gB,       Bs + l_off);
  gl_lds16(pb + gB2,      Bs + l_off + 4096);
  gl_lds16(pa + 32 + gA,  As + 8192 + l_off);
  gl_lds16(pa + 32 + gA2, As + 8192 + l_off + 4096);
  gl_lds16(pb + 32 + gB,  Bs + 8192 + l_off);
  gl_lds16(pb + 32 + gB2, Bs + 8192 + l_off + 4096);
  pa += 64; pb += 64;
  VMCNT4;
  BAR();

  const int NT = K >> 6;
  int buf = 0;
  for (int t = 0; t < NT; ++t) {
    const f16* Ac = As + buf * 16384;
    const f16* Bc = Bs + buf * 16384;
    f16* An = As + (buf ^ 1) * 16384;
    f16* Bn = Bs + (buf ^ 1) * 16384;
    const bool last = (t == NT - 1);
    f16x8 af[4], bf[4];

    // phase 1: kk0, i0-3 | stage next U1
    ld4(af, Ac, a_off);
    ld4(bf, Bc, b_off);
    if (!last) { gl_lds16(pa + gA, An + l_off); gl_lds16(pa + gA2, An + l_off + 4096); }
    BAR(); LGKM0;
    __builtin_amdgcn_s_setprio(1); mfma4x4<0>(acc, af, bf); __builtin_amdgcn_s_setprio(0);
    BAR();

    // phase 2: kk0, i4-7 | stage next U2 | vmcnt: cur kk1 resident
    ld4(af, Ac, a_off + 2048);
    if (!last) { gl_lds16(pb + gB, Bn + l_off); gl_lds16(pb + gB2, Bn + l_off + 4096); VMCNT4; }
    else VMCNT0;
    BAR(); LGKM0;
    __builtin_amdgcn_s_setprio(1); mfma4x4<4>(acc, af, bf); __builtin_amdgcn_s_setprio(0);
    BAR();

    // phase 3: kk1, i0-3 | stage next U3
    ld4(af, Ac, 8192 + a_off);
    ld4(bf, Bc, 8192 + b_off);
    if (!last) { gl_lds16(pa + 32 + gA, An + 8192 + l_off); gl_lds16(pa + 32 + gA2, An + 8192 + l_off + 4096); }
    BAR(); LGKM0;
    __builtin_amdgcn_s_setprio(1); mfma4x4<0>(acc, af, bf); __builtin_amdgcn_s_setprio(0);
    BAR();

    // phase 4: kk1, i4-7 | stage next U4 | vmcnt: next kk0 resident
    ld4(af, Ac, 8192 + a_off + 2048);
    if (!last) { gl_lds16(pb + 32 + gB, Bn + 8192 + l_off); gl_lds16(pb + 32 + gB2, Bn + 8192 + l_off + 4096); VMCNT4; }
    BAR(); LGKM0;
    __builtin_amdgcn_s_setprio(1); mfma4x4<4>(acc, af, bf); __builtin_amdgcn_s_setprio(0);
    BAR();

    pa += 64; pb += 64; buf ^= 1;
  }
}

// Split (double-f16) NT: C = Ah.Bh^T + Ah.Bl^T + Al.Bh^T, BK=32, 6 phases.
__device__ __forceinline__ void core_split(
    const f16* __restrict__ pah, const f16* __restrict__ pal,
    const f16* __restrict__ pbh, const f16* __restrict__ pbl,
    int K, int lda, int ldb, f16* LDS, f32x4 (&acc)[8][4])
{
  const int tid  = threadIdx.x;
  const int wave = tid >> 6;
  const int lane = tid & 63;
  const int quad = lane >> 4;
  const int col  = lane & 15;
  const int wm = (wave >> 2) * 128;
  const int wn = (wave & 3) * 64;
  const int l_off = wave * 512 + lane * 8;
  const int r0 = wave * 16 + (lane >> 2);
  const int c0 = ((lane & 3) - r0) & 3;
  const long gA  = (long)r0 * lda + c0 * 8;
  const long gA2 = gA + 128L * lda;
  const long gB  = (long)r0 * ldb + c0 * 8;
  const long gB2 = gB + 128L * ldb;
  const int a_off = (wm + col) * 32 + ((quad + col) & 3) * 8;
  const int b_off = (wn + col) * 32 + ((quad + col) & 3) * 8;

  f16* Ah = LDS;
  f16* Al = LDS + 16384;
  f16* Bh = LDS + 32768;
  f16* Bl = LDS + 49152;

  // prologue: tile 0 units U1=Ah U2=Bh U3=Bl U4=Al
  gl_lds16(pah + gA,  Ah + l_off);
  gl_lds16(pah + gA2, Ah + l_off + 4096);
  gl_lds16(pbh + gB,  Bh + l_off);
  gl_lds16(pbh + gB2, Bh + l_off + 4096);
  gl_lds16(pbl + gB,  Bl + l_off);
  gl_lds16(pbl + gB2, Bl + l_off + 4096);
  gl_lds16(pal + gA,  Al + l_off);
  gl_lds16(pal + gA2, Al + l_off + 4096);
  pah += 32; pal += 32; pbh += 32; pbl += 32;
  VMCNT4;
  BAR();

  const int NT = K >> 5;
  int buf = 0;
  for (int t = 0; t < NT; ++t) {
    const int bo = buf * 8192;
    const int bn = (buf ^ 1) * 8192;
    const bool last = (t == NT - 1);
    f16x8 ah[4], ah4[4], bh[4], bl[4], al[4], al4[4];

    // p1: hh i0-3 | stage next Ah
    ld4(ah, Ah + bo, a_off);
    ld4(bh, Bh + bo, b_off);
    if (!last) { gl_lds16(pah + gA, Ah + bn + l_off); gl_lds16(pah + gA2, Ah + bn + l_off + 4096); }
    BAR(); LGKM0;
    __builtin_amdgcn_s_setprio(1); mfma4x4<0>(acc, ah, bh); __builtin_amdgcn_s_setprio(0);
    BAR();

    // p2: hh i4-7 | stage next Bh | vmcnt: cur Bl,Al resident
    ld4(ah4, Ah + bo, a_off + 2048);
    if (!last) { gl_lds16(pbh + gB, Bh + bn + l_off); gl_lds16(pbh + gB2, Bh + bn + l_off + 4096); VMCNT4; }
    else VMCNT0;
    BAR(); LGKM0;
    __builtin_amdgcn_s_setprio(1); mfma4x4<4>(acc, ah4, bh); __builtin_amdgcn_s_setprio(0);
    BAR();

    // p3: h.l i0-3 | stage next Bl
    ld4(bl, Bl + bo, b_off);
    if (!last) { gl_lds16(pbl + gB, Bl + bn + l_off); gl_lds16(pbl + gB2, Bl + bn + l_off + 4096); }
    BAR(); LGKM0;
    __builtin_amdgcn_s_setprio(1); mfma4x4<0>(acc, ah, bl); __builtin_amdgcn_s_setprio(0);
    BAR();

    // p4: h.l i4-7 | stage next Al
    ld4(al, Al + bo, a_off);
    if (!last) { gl_lds16(pal + gA, Al + bn + l_off); gl_lds16(pal + gA2, Al + bn + l_off + 4096); }
    BAR(); LGKM0;
    __builtin_amdgcn_s_setprio(1); mfma4x4<4>(acc, ah4, bl); __builtin_amdgcn_s_setprio(0);
    BAR();

    // p5: l.h i0-3
    ld4(al4, Al + bo, a_off + 2048);
    BAR(); LGKM0;
    __builtin_amdgcn_s_setprio(1); mfma4x4<0>(acc, al, bh); __builtin_amdgcn_s_setprio(0);
    BAR();

    // p6: l.h i4-7 | vmcnt: next Ah,Bh resident
    if (!last) VMCNT4;
    BAR();
    __builtin_amdgcn_s_setprio(1); mfma4x4<4>(acc, al4, bh); __builtin_amdgcn_s_setprio(0);
    BAR();

    pah += 32; pal += 32; pbh += 32; pbl += 32; buf ^= 1;
  }
}

__device__ __forceinline__ void store8_f16(f16* C, long ldc, long tm, long tn,
                                           f32x4 (&acc)[8][4], float scale) {
  const int tid = threadIdx.x, wave = tid >> 6, lane = tid & 63;
  const long cm = tm + (long)((wave >> 2) * 128 + (lane >> 4) * 4);
  const long cn = tn + (long)((wave & 3) * 64 + (lane & 15));
#pragma unroll
  for (int i = 0; i < 8; ++i)
#pragma unroll
    for (int r = 0; r < 4; ++r) {
      const long rowb = (cm + i * 16 + r) * ldc;
#pragma unroll
      for (int j = 0; j < 4; ++j)
        C[rowb + cn + j * 16] = (f16)(acc[i][j][r] * scale);
    }
}

__device__ __forceinline__ void store8_split(f16* Ch, f16* Cl, long ldc, long tm, long tn,
                                             f32x4 (&acc)[8][4]) {
  const int tid = threadIdx.x, wave = tid >> 6, lane = tid & 63;
  const long cm = tm + (long)((wave >> 2) * 128 + (lane >> 4) * 4);
  const long cn = tn + (long)((wave & 3) * 64 + (lane & 15));
#pragma unroll
  for (int i = 0; i < 8; ++i)
#pragma unroll
    for (int r = 0; r < 4; ++r) {
      const long rowb = (cm + i * 16 + r) * ldc;
#pragma unroll
      for (int j = 0; j < 4; ++j) {
        const float v = acc[i][j][r];
        const f16 hi = (f16)v;
        Ch[rowb + cn + j * 16] = hi;
        Cl[rowb + cn + j * 16] = (f16)(v - (float)hi);
      }
    }
}

// Generic plain 256^2 NT-GEMM wrapper (used for the 8-way K-split out-GEMM).
template <int CMODE>
__global__ __launch_bounds__(512, 2) void gemm8p(
    const f16* __restrict__ A, const f16* __restrict__ B, void* __restrict__ C,
    int K, int lda, int ldb, int ldc, int ZB,
    long sA1, long sA2, long sB1, long sB2, long sC1, long sC2, float scale)
{
  __shared__ f16 LDS[65536];
  const int z  = blockIdx.z;
  const int z1 = z % ZB;
  const int z2 = z / ZB;
  const long offA = (long)z1 * sA1 + (long)z2 * sA2;
  const long offB = (long)z1 * sB1 + (long)z2 * sB2;
  const long offC = (long)z1 * sC1 + (long)z2 * sC2;
  const long tm = (long)blockIdx.x * 256;
  const long tn = (long)blockIdx.y * 256;

  f32x4 acc[8][4];
#pragma unroll
  for (int i = 0; i < 8; ++i)
#pragma unroll
    for (int j = 0; j < 4; ++j) acc[i][j] = (f32x4){0.f, 0.f, 0.f, 0.f};

  core_plain(A + offA + tm * lda, B + offB + tn * ldb, K, lda, ldb,
             LDS, LDS + 32768, acc);
  store8_f16((f16*)C + offC, ldc, tm, tn, acc, scale);
}

// ---------------------------------------------------------------------------
// y_vproj (8-phase): blocks [0, G*64): y[slot] = X(split) @ MT[slot]^T
//                    blocks [G*64, +4G*16): vT[hh][b] = WvT[hh] @ Xh[b]^T
// ---------------------------------------------------------------------------
__global__ __launch_bounds__(512, 2) void y_vproj8(
    const f16* __restrict__ Xh, const f16* __restrict__ Xl,
    const f16* __restrict__ MTh, const f16* __restrict__ MTl,
    f16* __restrict__ yh, f16* __restrict__ yl,
    const f16* __restrict__ WvT, f16* __restrict__ vT, int G)
{
  __shared__ f16 LDS[65536];
  const long M1 = 1024 * 1024;
  const int bx = blockIdx.x;
  const int yB = G * 64;

  f32x4 acc[8][4];
#pragma unroll
  for (int i = 0; i < 8; ++i)
#pragma unroll
    for (int j = 0; j < 4; ++j) acc[i][j] = (f32x4){0.f, 0.f, 0.f, 0.f};

  if (bx < yB) {
    const int slot = bx >> 6;
    const int t = bx & 63;
    const long tm = (long)(t & 15) * 256;
    const long tn = (long)(t >> 4) * 256;
    core_split(Xh + tm * 1024, Xl + tm * 1024,
               MTh + (long)slot * M1 + tn * 1024, MTl + (long)slot * M1 + tn * 1024,
               1024, 1024, 1024, LDS, acc);
    store8_split(yh + (long)slot * 4 * M1, yl + (long)slot * 4 * M1, 1024, tm, tn, acc);
  } else {
    const int bx2 = bx - yB;
    const int pair = bx2 >> 4;
    const int hh = pair >> 2, b = pair & 3;
    const int t = bx2 & 15;
    const long tm = (long)(t & 3) * 256;
    const long tn = (long)(t >> 2) * 256;
    core_plain(WvT + (long)hh * M1 + tm * 1024, Xh + (long)b * M1 + tn * 1024,
               1024, 1024, 1024, LDS, LDS + 32768, acc);
    store8_f16(vT + (long)hh * 4 * M1 + (long)b * M1, 1024, tm, tn, acc, 1.0f);
  }
}

// ---------------------------------------------------------------------------
// Fused pipeline dispatch (8-phase): PV of group g + y/vT of group g+1.
//   [0, G*64):        y(g+1) split
//   [G*64, +4G*16):   vT(g+1) into vT_w
//   [.., +4G*16):     PV(g): h2pv = P @ vT_r^T (ldc 8192)
// ---------------------------------------------------------------------------
__global__ __launch_bounds__(512, 2) void pv_y_vproj8(
    const f16* __restrict__ Xh, const f16* __restrict__ Xl,
    const f16* __restrict__ MTh, const f16* __restrict__ MTl,
    f16* __restrict__ yh, f16* __restrict__ yl,
    const f16* __restrict__ WvT, f16* __restrict__ vT_w,
    const f16* __restrict__ P, const f16* __restrict__ vT_r,
    f16* __restrict__ h2pv, int G)
{
  __shared__ f16 LDS[65536];
  const long M1 = 1024 * 1024;
  const int bx = blockIdx.x;
  const int yB = G * 64;
  const int vB = 4 * G * 16;

  f32x4 acc[8][4];
#pragma unroll
  for (int i = 0; i < 8; ++i)
#pragma unroll
    for (int j = 0; j < 4; ++j) acc[i][j] = (f32x4){0.f, 0.f, 0.f, 0.f};

  if (bx < yB) {
    const int slot = bx >> 6;
    const int t = bx & 63;
    const long tm = (long)(t & 15) * 256;
    const long tn = (long)(t >> 4) * 256;
    core_split(Xh + tm * 1024, Xl + tm * 1024,
               MTh + (long)slot * M1 + tn * 1024, MTl + (long)slot * M1 + tn * 1024,
               1024, 1024, 1024, LDS, acc);
    store8_split(yh + (long)slot * 4 * M1, yl + (long)slot * 4 * M1, 1024, tm, tn, acc);
  } else if (bx < yB + vB) {
    const int bx2 = bx - yB;
    const int pair = bx2 >> 4;
    const int hh = pair >> 2, b = pair & 3;
    const int t = bx2 & 15;
    const long tm = (long)(t & 3) * 256;
    const long tn = (long)(t >> 2) * 256;
    core_plain(WvT + (long)hh * M1 + tm * 1024, Xh + (long)b * M1 + tn * 1024,
               1024, 1024, 1024, LDS, LDS + 32768, acc);
    store8_f16(vT_w + (long)hh * 4 * M1 + (long)b * M1, 1024, tm, tn, acc, 1.0f);
  } else {
    const int bx2 = bx - yB - vB;
    const int pair = bx2 >> 4;
    const int hh = pair >> 2, b = pair & 3;
    const int t = bx2 & 15;
    const long tm = (long)(t & 3) * 256;
    const long tn = (long)(t >> 2) * 256;
    core_plain(P + (long)hh * 4 * M1 + (long)b * M1 + tm * 1024,
               vT_r + (long)hh * 4 * M1 + (long)b * M1 + tn * 1024,
               1024, 1024, 1024, LDS, LDS + 32768, acc);
    store8_f16(h2pv + (long)b * 1024 * 8192 + (long)hh * 1024, 8192, tm, tn, acc, 1.0f);
  }
}

// out[i] = sum_{z<8} (float)p[z*4M + i]   (fp16 partials -> fp32 out)
__global__ __launch_bounds__(256) void reduce8(const f16* __restrict__ p,
                                               float* __restrict__ out) {
  const long i = ((long)blockIdx.x * 256 + threadIdx.x) * 4;
  const long S = 4L * 1024 * 1024;
  float4 o = {0.f, 0.f, 0.f, 0.f};
#pragma unroll
  for (int z = 0; z < 8; ++z) {
    const f16x4 v = *(const f16x4*)(p + z * S + i);
    o.x += (float)v[0]; o.y += (float)v[1]; o.z += (float)v[2]; o.w += (float)v[3];
  }
  *(float4*)(out + i) = o;
}

// Row softmax over 1024-wide fp32 rows -> fp16 P. One 256-thread block/row.
__global__ __launch_bounds__(256) void softmax_rows(const float* __restrict__ Sc,
                                                    f16* __restrict__ P) {
  const long row = blockIdx.x;
  const int tid = threadIdx.x;
  const float4 v = ((const float4*)(Sc + row * 1024))[tid];
  float m = fmaxf(fmaxf(v.x, v.y), fmaxf(v.z, v.w));
#pragma unroll
  for (int off = 32; off > 0; off >>= 1) m = fmaxf(m, __shfl_xor(m, off, 64));
  __shared__ float red[4], red2[4];
  const int wv = tid >> 6, ln = tid & 63;
  if (ln == 0) red[wv] = m;
  __syncthreads();
  m = fmaxf(fmaxf(red[0], red[1]), fmaxf(red[2], red[3]));
  const float e0 = __expf(v.x - m), e1 = __expf(v.y - m);
  const float e2 = __expf(v.z - m), e3 = __expf(v.w - m);
  float s = e0 + e1 + e2 + e3;
#pragma unroll
  for (int off = 32; off > 0; off >>= 1) s += __shfl_xor(s, off, 64);
  if (ln == 0) red2[wv] = s;
  __syncthreads();
  s = red2[0] + red2[1] + red2[2] + red2[3];
  const float inv = 1.0f / s;
  f16x4 o = {(f16)(e0 * inv), (f16)(e1 * inv), (f16)(e2 * inv), (f16)(e3 * inv)};
  *(f16x4*)(P + row * 1024 + tid * 4) = o;
}

// ---------------------------------------------------------------------------
// One upfront prep dispatch:
//   [0,4096):       X  split cvt (4M)
//   [4096,12288):   WQ split cvt (8M)
//   [12288,20480):  WK split cvt (8M)
//   [20480,22528):  WV transpose (8 heads x 256 64x64 tiles) -> WvTa
//   [22528,24576):  WO transpose (8192x1024 -> WoTa[e][r], ld 8192)
// ---------------------------------------------------------------------------
__global__ __launch_bounds__(256) void prep_all(
    const float* __restrict__ X, const float* __restrict__ WQ,
    const float* __restrict__ WK, const float* __restrict__ WV,
    const float* __restrict__ WO,
    f16* __restrict__ Xh, f16* __restrict__ Xl,
    f16* __restrict__ Wqh, f16* __restrict__ Wql,
    f16* __restrict__ Wkh, f16* __restrict__ Wkl,
    f16* __restrict__ WvTa, f16* __restrict__ WoTa)
{
  __shared__ float t[64][65];
  const int bx = blockIdx.x;
  const int tid = threadIdx.x;
  const long M1 = 1024 * 1024;

  if (bx < 20480) {
    const float* src; f16 *hi, *lo; long i;
    if (bx < 4096)       { src = X;  hi = Xh;  lo = Xl;  i = (long)bx * 1024; }
    else if (bx < 12288) { src = WQ; hi = Wqh; lo = Wql; i = (long)(bx - 4096) * 1024; }
    else                 { src = WK; hi = Wkh; lo = Wkl; i = (long)(bx - 12288) * 1024; }
    i += tid * 4;
    const float4 v = *(const float4*)(src + i);
    f16 h0 = (f16)v.x, h1 = (f16)v.y, h2 = (f16)v.z, h3 = (f16)v.w;
    f16x4 oh = {h0, h1, h2, h3};
    f16x4 ol = {(f16)(v.x - (float)h0), (f16)(v.y - (float)h1),
                (f16)(v.z - (float)h2), (f16)(v.w - (float)h3)};
    *(f16x4*)(hi + i) = oh;
    *(f16x4*)(lo + i) = ol;
  } else if (bx < 22528) {
    const int t0 = bx - 20480;
    const int head = t0 >> 8;
    const int tile = t0 & 255;
    const int r0 = (tile & 15) * 64;
    const int c0 = (tile >> 4) * 64;
    const float* in = WV + (long)head * M1;
#pragma unroll
    for (int it = 0; it < 16; ++it) {
      const int idx = it * 256 + tid;
      const int rr = idx >> 6, cc = idx & 63;
      t[rr][cc] = in[(long)(r0 + rr) * 1024 + (c0 + cc)];
    }
    __syncthreads();
#pragma unroll
    for (int it = 0; it < 16; ++it) {
      const int idx = it * 256 + tid;
      const int rr = idx >> 6, cc = idx & 63;
      WvTa[(long)head * M1 + (long)(c0 + rr) * 1024 + (r0 + cc)] = (f16)t[cc][rr];
    }
  } else {
    const int t0 = bx - 22528;
    const int rb = t0 & 127, cb = t0 >> 7;
    const int r0 = rb * 64, c0 = cb * 64;
#pragma unroll
    for (int it = 0; it < 16; ++it) {
      const int idx = it * 256 + tid;
      const int rr = idx >> 6, cc = idx & 63;
      t[rr][cc] = WO[(long)(r0 + rr) * 1024 + (c0 + cc)];
    }
    __syncthreads();
#pragma unroll
    for (int it = 0; it < 16; ++it) {
      const int idx = it * 256 + tid;
      const int rr = idx >> 6, cc = idx & 63;
      WoTa[(long)(c0 + rr) * 8192 + (r0 + cc)] = (f16)t[cc][rr];
    }
  }
}

// ---------------------------------------------------------------------------
// B=4, S=1024, D=1024, H=8.  scores = 32 * X M X^T with M = Wq.Wk^T.
// Double-fp16 score path (absmax 0.0625 verified R3-R7). G=2 head groups.
// Heavy fused dispatches (y_vproj, pv_y_vproj) + out-GEMM now use the
// 256^2 8-phase counted-vmcnt cores; MT / scores / final PV stay on the
// 128^2 kernels (128-tile dispatches -> 256^2 would idle half the CUs).
// ---------------------------------------------------------------------------
extern "C" void kernel_launch(void* const* d_in, const int* in_sizes, int n_in,
                              void* d_out, int out_size, void* d_ws, size_t ws_size,
                              hipStream_t stream) {
  const float* X  = (const float*)d_in[0];
  const float* WQ = (const float*)d_in[2];
  const float* WK = (const float*)d_in[3];
  const float* WV = (const float*)d_in[4];
  const float* WO = (const float*)d_in[5];
  float* out = (float*)d_out;

  const long M1 = 1024 * 1024;
  const long MB = 1024 * 1024;
  const int G = 2;

  const bool PIPE = ws_size >= (size_t)256 * MB;
  if (ws_size < (size_t)224 * MB) return;  // diagnostic (ws >= 228 MiB known)

  f16* Xh   = (f16*)d_ws;
  f16* Xl   = Xh + 4 * M1;
  f16* MTh  = Xl + 4 * M1;
  f16* MTl  = MTh + 8 * M1;
  f16* h2a  = MTl + 8 * M1;
  f16* WoTa = h2a + 32 * M1;
  f16* WvTa = WoTa + 8 * M1;
  f16* yh   = WvTa + 8 * M1;
  f16* yl   = yh + 8 * M1;
  f16* vTA  = yl + 8 * M1;
  f16* vTB  = PIPE ? vTA + 8 * M1 : vTA;
  float* Sc = (float*)(vTB + 8 * M1);
  f16* P    = PIPE ? (f16*)(Sc + 8 * M1) : yh;
  f16* Wqh = yh;
  f16* Wql = yh + 8 * M1;
  f16* Wkh = yh + 16 * M1;
  f16* Wkl = yh + 24 * M1;
  f16* partials = yh;  // 8 x 4M f16

  prep_all<<<24576, 256, 0, stream>>>(X, WQ, WK, WV, WO,
                                      Xh, Xl, Wqh, Wql, Wkh, Wkl, WvTa, WoTa);
  // MT[h][d2][d1] = sum_e Wk[h][d2][e] * Wq[h][d1][e]
  gemm_nt3<0><<<dim3(8, 8, 8), 256, 0, stream>>>(Wkh, Wkl, Wqh, Wql, MTh, MTl,
                                                 1024, 1024, 8,
                                                 M1, 0, M1, 0, M1, 0, 1.0f);

  if (PIPE) {
    f16* vT_cur = vTA;
    f16* vT_nxt = vTB;
    y_vproj8<<<G * 64 + 4 * G * 16, 512, 0, stream>>>(
        Xh, Xl, MTh, MTl, yh, yl, WvTa, vT_cur, G);
    for (int g = 0; g < 4; ++g) {
      const long h0 = (long)g * G;
      gemm_nt3<1><<<dim3(8, 8, 4 * G), 256, 0, stream>>>(yh, yl, Xh, Xl, Sc, (f16*)0,
                                                         1024, 1024, 4,
                                                         M1, 4 * M1, M1, 0,
                                                         M1, 4 * M1, 32.0f);
      softmax_rows<<<G * 4096, 256, 0, stream>>>(Sc, P);
      if (g < 3) {
        const long h0n = h0 + G;
        pv_y_vproj8<<<G * 64 + 2 * 4 * G * 16, 512, 0, stream>>>(
            Xh, Xl, MTh + h0n * M1, MTl + h0n * M1, yh, yl,
            WvTa + h0n * M1, vT_nxt, P, vT_cur, h2a + h0 * 1024, G);
        f16* tmp = vT_cur; vT_cur = vT_nxt; vT_nxt = tmp;
      } else {
        gemm_nt<0><<<dim3(8, 8, 4 * G), 256, 0, stream>>>(P, vT_cur, h2a + h0 * 1024,
                                                          1024, 1024, 1024, 8192, 4,
                                                          M1, 4 * M1, M1, 4 * M1,
                                                          (long)1024 * 8192, 1024, 1.0f);
      }
    }
  } else {
    for (int g = 0; g < 4; ++g) {
      const long h0 = (long)g * G;
      y_vproj8<<<G * 64 + 4 * G * 16, 512, 0, stream>>>(
          Xh, Xl, MTh + h0 * M1, MTl + h0 * M1, yh, yl, WvTa + h0 * M1, vTA, G);
      gemm_nt3<1><<<dim3(8, 8, 4 * G), 256, 0, stream>>>(yh, yl, Xh, Xl, Sc, (f16*)0,
                                                         1024, 1024, 4,
                                                         M1, 4 * M1, M1, 0,
                                                         M1, 4 * M1, 32.0f);
      softmax_rows<<<G * 4096, 256, 0, stream>>>(Sc, P);
      gemm_nt<0><<<dim3(8, 8, 4 * G), 256, 0, stream>>>(P, vTA, h2a + h0 * 1024,
                                                        1024, 1024, 1024, 8192, 4,
                                                        M1, 4 * M1, M1, 4 * M1,
                                                        (long)1024 * 8192, 1024, 1.0f);
    }
  }

  // 8-way K-split out-GEMM (256^2 8-phase, 512 blocks) + reduce
  gemm8p<0><<<dim3(16, 4, 8), 512, 0, stream>>>(h2a, WoTa, partials,
                                                1024, 8192, 8192, 1024, 8,
                                                1024, 0, 1024, 0, 4 * M1, 0, 1.0f);
  reduce8<<<4096, 256, 0, stream>>>(partials, out);
}

// Round 2
// 925.813 us; speedup vs baseline: 1.1160x; 1.0439x over previous
//
#include <hip/hip_runtime.h>

typedef _Float16 f16;
typedef _Float16 f16x4 __attribute__((ext_vector_type(4)));
typedef _Float16 f16x8 __attribute__((ext_vector_type(8)));
typedef float    f32x4 __attribute__((ext_vector_type(4)));

#define AS1 __attribute__((address_space(1)))
#define AS3 __attribute__((address_space(3)))

__device__ __forceinline__ void gl_lds16(const void* g, void* l) {
  __builtin_amdgcn_global_load_lds((const AS1 void*)g, (AS3 void*)l, 16, 0, 0);
}

#define VMCNT4 asm volatile("s_waitcnt vmcnt(4)" ::: "memory")
#define VMCNT0 asm volatile("s_waitcnt vmcnt(0)" ::: "memory")
#define LGKM0  asm volatile("s_waitcnt lgkmcnt(0)" ::: "memory")
#define BAR()  __builtin_amdgcn_s_barrier()

// ===========================================================================
// OLD 128x128 (m97-structure) kernels — retained for the 128-tile-count
// dispatches (MT, scores, final PV).
// ===========================================================================
template <int CMODE>
__global__ __launch_bounds__(256) void gemm_nt(
    const f16* __restrict__ A, const f16* __restrict__ B, void* __restrict__ C,
    int K, int lda, int ldb, int ldc, int ZB,
    long sA1, long sA2, long sB1, long sB2, long sC1, long sC2, float scale)
{
  __shared__ __align__(16) f16 As[128 * 32];
  __shared__ __align__(16) f16 Bs[128 * 32];

  const int tid  = threadIdx.x;
  const int wave = tid >> 6;
  const int lane = tid & 63;
  const int quad = lane >> 4;
  const int col  = lane & 15;
  const int wm = (wave & 1) * 64;
  const int wn = (wave >> 1) * 64;

  const int z  = blockIdx.z;
  const int z1 = z % ZB;
  const int z2 = z / ZB;
  const long offA = (long)z1 * sA1 + (long)z2 * sA2;
  const long offB = (long)z1 * sB1 + (long)z2 * sB2;
  const long offC = (long)z1 * sC1 + (long)z2 * sC2;

  const long tile_m = (long)blockIdx.x * 128;
  const long tile_n = (long)blockIdx.y * 128;

  const int rstage = wave * 16 + (lane >> 2);
  const int kq = ((lane & 3) - ((lane >> 3) & 3)) & 3;
  const int kstage = kq * 8;
  const int lstage = (lane & 3) * 8;
  const f16* pa = A + offA + (tile_m + rstage) * (long)lda + kstage;
  const f16* pb = B + offB + (tile_n + rstage) * (long)ldb + kstage;
  f16* la0 = &As[rstage * 32 + lstage];
  f16* la1 = &As[(rstage + 64) * 32 + lstage];
  f16* lb0 = &Bs[rstage * 32 + lstage];
  f16* lb1 = &Bs[(rstage + 64) * 32 + lstage];
  const long skipA = 64L * lda;
  const long skipB = 64L * ldb;

  const int sA_sw = (quad + ((col >> 1) & 3)) & 3;

  f32x4 acc[4][4];
#pragma unroll
  for (int i = 0; i < 4; ++i)
#pragma unroll
    for (int j = 0; j < 4; ++j) acc[i][j] = (f32x4){0.f, 0.f, 0.f, 0.f};

  for (int k0 = 0; k0 < K; k0 += 32) {
    gl_lds16(pa, la0);
    gl_lds16(pa + skipA, la1);
    gl_lds16(pb, lb0);
    gl_lds16(pb + skipB, lb1);
    pa += 32;
    pb += 32;
    __syncthreads();

    const f16x8* A8 = (const f16x8*)As;
    const f16x8* B8 = (const f16x8*)Bs;
    f16x8 af[4], bf[4];
#pragma unroll
    for (int i = 0; i < 4; ++i) af[i] = A8[(wm + i * 16 + col) * 4 + sA_sw];
#pragma unroll
    for (int j = 0; j < 4; ++j) bf[j] = B8[(wn + j * 16 + col) * 4 + sA_sw];
#pragma unroll
    for (int i = 0; i < 4; ++i)
#pragma unroll
      for (int j = 0; j < 4; ++j)
        acc[i][j] = __builtin_amdgcn_mfma_f32_16x16x32_f16(af[i], bf[j], acc[i][j], 0, 0, 0);
    __syncthreads();
  }

  const long cm = tile_m + wm + quad * 4;
  const long cn = tile_n + wn + col;
  if (CMODE == 0) {
    f16* Cp = (f16*)C + offC;
#pragma unroll
    for (int i = 0; i < 4; ++i)
#pragma unroll
      for (int r = 0; r < 4; ++r) {
        const long rowb = (cm + i * 16 + r) * (long)ldc;
#pragma unroll
        for (int j = 0; j < 4; ++j)
          Cp[rowb + cn + j * 16] = (f16)(acc[i][j][r] * scale);
      }
  } else if (CMODE == 1) {
    float* Cp = (float*)C + offC;
#pragma unroll
    for (int i = 0; i < 4; ++i)
#pragma unroll
      for (int r = 0; r < 4; ++r) {
        const long rowb = (cm + i * 16 + r) * (long)ldc;
#pragma unroll
        for (int j = 0; j < 4; ++j)
          Cp[rowb + cn + j * 16] = acc[i][j][r] * scale;
      }
  } else {
    float* Cp = (float*)C + offC;
#pragma unroll
    for (int i = 0; i < 4; ++i)
#pragma unroll
      for (int r = 0; r < 4; ++r) {
        const long rowb = (cm + i * 16 + r) * (long)ldc;
#pragma unroll
        for (int j = 0; j < 4; ++j)
          Cp[rowb + cn + j * 16] += acc[i][j][r] * scale;
      }
  }
}

template <int CMODE>
__global__ __launch_bounds__(256) void gemm_nt3(
    const f16* __restrict__ Ah, const f16* __restrict__ Al,
    const f16* __restrict__ Bh, const f16* __restrict__ Bl,
    void* __restrict__ C, f16* __restrict__ Cl,
    int K, int ldc, int ZB,
    long sA1, long sA2, long sB1, long sB2, long sC1, long sC2, float scale)
{
  __shared__ __align__(16) f16 Ash[128 * 32];
  __shared__ __align__(16) f16 Asl[128 * 32];
  __shared__ __align__(16) f16 Bsh[128 * 32];
  __shared__ __align__(16) f16 Bsl[128 * 32];

  const int tid  = threadIdx.x;
  const int wave = tid >> 6;
  const int lane = tid & 63;
  const int quad = lane >> 4;
  const int col  = lane & 15;
  const int wm = (wave & 1) * 64;
  const int wn = (wave >> 1) * 64;

  const int z  = blockIdx.z;
  const int z1 = z % ZB;
  const int z2 = z / ZB;
  const long offA = (long)z1 * sA1 + (long)z2 * sA2;
  const long offB = (long)z1 * sB1 + (long)z2 * sB2;
  const long offC = (long)z1 * sC1 + (long)z2 * sC2;

  const long tile_m = (long)blockIdx.x * 128;
  const long tile_n = (long)blockIdx.y * 128;

  const int rstage = wave * 16 + (lane >> 2);
  const int kq = ((lane & 3) - ((lane >> 3) & 3)) & 3;
  const int kstage = kq * 8;
  const int lstage = (lane & 3) * 8;
  const long aoff = offA + (tile_m + rstage) * (long)K + kstage;
  const long boff = offB + (tile_n + rstage) * (long)K + kstage;
  const f16* pah = Ah + aoff;
  const f16* pal = Al + aoff;
  const f16* pbh = Bh + boff;
  const f16* pbl = Bl + boff;
  const int lds_o = rstage * 32 + lstage;
  const long skip = 64L * K;

  const int sA_sw = (quad + ((col >> 1) & 3)) & 3;

  f32x4 acc[4][4];
#pragma unroll
  for (int i = 0; i < 4; ++i)
#pragma unroll
    for (int j = 0; j < 4; ++j) acc[i][j] = (f32x4){0.f, 0.f, 0.f, 0.f};

  for (int k0 = 0; k0 < K; k0 += 32) {
    gl_lds16(pah, &Ash[lds_o]);
    gl_lds16(pah + skip, &Ash[lds_o + 64 * 32]);
    gl_lds16(pal, &Asl[lds_o]);
    gl_lds16(pal + skip, &Asl[lds_o + 64 * 32]);
    gl_lds16(pbh, &Bsh[lds_o]);
    gl_lds16(pbh + skip, &Bsh[lds_o + 64 * 32]);
    gl_lds16(pbl, &Bsl[lds_o]);
    gl_lds16(pbl + skip, &Bsl[lds_o + 64 * 32]);
    pah += 32; pal += 32; pbh += 32; pbl += 32;
    __syncthreads();

    const f16x8* A8h = (const f16x8*)Ash;
    const f16x8* A8l = (const f16x8*)Asl;
    const f16x8* B8h = (const f16x8*)Bsh;
    const f16x8* B8l = (const f16x8*)Bsl;
    f16x8 ah[4], al[4], bh[4], bl[4];
#pragma unroll
    for (int i = 0; i < 4; ++i) {
      const int idx = (wm + i * 16 + col) * 4 + sA_sw;
      ah[i] = A8h[idx];
      al[i] = A8l[idx];
    }
#pragma unroll
    for (int j = 0; j < 4; ++j) {
      const int idx = (wn + j * 16 + col) * 4 + sA_sw;
      bh[j] = B8h[idx];
      bl[j] = B8l[idx];
    }
#pragma unroll
    for (int i = 0; i < 4; ++i)
#pragma unroll
      for (int j = 0; j < 4; ++j) {
        acc[i][j] = __builtin_amdgcn_mfma_f32_16x16x32_f16(ah[i], bh[j], acc[i][j], 0, 0, 0);
        acc[i][j] = __builtin_amdgcn_mfma_f32_16x16x32_f16(ah[i], bl[j], acc[i][j], 0, 0, 0);
        acc[i][j] = __builtin_amdgcn_mfma_f32_16x16x32_f16(al[i], bh[j], acc[i][j], 0, 0, 0);
      }
    __syncthreads();
  }

  const long cm = tile_m + wm + quad * 4;
  const long cn = tile_n + wn + col;
  if (CMODE == 0) {
    f16* Ch = (f16*)C + offC;
    f16* Clp = Cl + offC;
#pragma unroll
    for (int i = 0; i < 4; ++i)
#pragma unroll
      for (int r = 0; r < 4; ++r) {
        const long rowb = (cm + i * 16 + r) * (long)ldc;
#pragma unroll
        for (int j = 0; j < 4; ++j) {
          const float v = acc[i][j][r] * scale;
          const f16 hi = (f16)v;
          Ch[rowb + cn + j * 16] = hi;
          Clp[rowb + cn + j * 16] = (f16)(v - (float)hi);
        }
      }
  } else {
    float* Cp = (float*)C + offC;
#pragma unroll
    for (int i = 0; i < 4; ++i)
#pragma unroll
      for (int r = 0; r < 4; ++r) {
        const long rowb = (cm + i * 16 + r) * (long)ldc;
#pragma unroll
        for (int j = 0; j < 4; ++j)
          Cp[rowb + cn + j * 16] = acc[i][j][r] * scale;
      }
  }
}

// ===========================================================================
// 256x256 8-phase cores (T3+T4 counted vmcnt + T5 setprio).
// R2 fix: chunk rotation by (row>>1) — NOT row — so each consecutive
// 8-lane group of a ds_read_b128 hits all 8 16B-granules of a 128B line
// (lane-order service). R1's per-row rotation gave 2-way collisions in
// every 8-lane group -> 6.29M SQ_LDS_BANK_CONFLICT. Stage-side: lane
// fetches global chunk c0 = ((lane&3) - ((lane>>3)&3)) & 3 (linear LDS
// dest, m104/m173); read slot = (quad + ((col>>1)&3)) & 3 — identical
// derivation to the verified 128^2 swizzle.
// ===========================================================================

template <int BASE>
__device__ __forceinline__ void mfma4x4(f32x4 (&acc)[8][4],
                                        const f16x8 (&a)[4], const f16x8 (&b)[4]) {
#pragma unroll
  for (int i = 0; i < 4; ++i)
#pragma unroll
    for (int j = 0; j < 4; ++j)
      acc[BASE + i][j] =
          __builtin_amdgcn_mfma_f32_16x16x32_f16(a[i], b[j], acc[BASE + i][j], 0, 0, 0);
}

__device__ __forceinline__ void ld4(f16x8 (&d)[4], const f16* base, int off) {
#pragma unroll
  for (int k = 0; k < 4; ++k) d[k] = *(const f16x8*)(base + off + k * 512);
}

// Plain NT: C = A(MxK) . B(NxK)^T, BK=64, 4 phases/K-tile, 16 MFMA each.
__device__ __forceinline__ void core_plain(
    const f16* __restrict__ pa, const f16* __restrict__ pb,
    int K, int lda, int ldb, f16* As, f16* Bs, f32x4 (&acc)[8][4])
{
  const int tid  = threadIdx.x;
  const int wave = tid >> 6;
  const int lane = tid & 63;
  const int quad = lane >> 4;
  const int col  = lane & 15;
  const int wm = (wave >> 2) * 128;
  const int wn = (wave & 3) * 64;
  const int l_off = wave * 512 + lane * 8;
  const int r0 = wave * 16 + (lane >> 2);
  const int c0 = ((lane & 3) - ((lane >> 3) & 3)) & 3;  // rotation by row>>1
  const long gA  = (long)r0 * lda + c0 * 8;
  const long gA2 = gA + 128L * lda;
  const long gB  = (long)r0 * ldb + c0 * 8;
  const long gB2 = gB + 128L * ldb;
  const int sw = ((quad + ((col >> 1) & 3)) & 3) * 8;
  const int a_off = (wm + col) * 32 + sw;
  const int b_off = (wn + col) * 32 + sw;

  // prologue: tile 0 units U1=A.kk0 U2=B.kk0 U3=A.kk1 U4=B.kk1
  gl_lds16(pa + gA,       As + l_off);
  gl_lds16(pa + gA2,      As + l_off + 4096);
  gl_lds16(pb + gB,       Bs + l_off);
  gl_lds16(pb + gB2,      Bs + l_off + 4096);
  gl_lds16(pa + 32 + gA,  As + 8192 + l_off);
  gl_lds16(pa + 32 + gA2, As + 8192 + l_off + 4096);
  gl_lds16(pb + 32 + gB,  Bs + 8192 + l_off);
  gl_lds16(pb + 32 + gB2, Bs + 8192 + l_off + 4096);
  pa += 64; pb += 64;
  VMCNT4;
  BAR();

  const int NT = K >> 6;
  int buf = 0;
  for (int t = 0; t < NT; ++t) {
    const f16* Ac = As + buf * 16384;
    const f16* Bc = Bs + buf * 16384;
    f16* An = As + (buf ^ 1) * 16384;
    f16* Bn = Bs + (buf ^ 1) * 16384;
    const bool last = (t == NT - 1);
    f16x8 af[4], bf[4];

    // phase 1: kk0, i0-3 | stage next U1
    ld4(af, Ac, a_off);
    ld4(bf, Bc, b_off);
    if (!last) { gl_lds16(pa + gA, An + l_off); gl_lds16(pa + gA2, An + l_off + 4096); }
    BAR(); LGKM0;
    __builtin_amdgcn_s_setprio(1); mfma4x4<0>(acc, af, bf); __builtin_amdgcn_s_setprio(0);
    BAR();

    // phase 2: kk0, i4-7 | stage next U2 | vmcnt: cur kk1 resident
    ld4(af, Ac, a_off + 2048);
    if (!last) { gl_lds16(pb + gB, Bn + l_off); gl_lds16(pb + gB2, Bn + l_off + 4096); VMCNT4; }
    else VMCNT0;
    BAR(); LGKM0;
    __builtin_amdgcn_s_setprio(1); mfma4x4<4>(acc, af, bf); __builtin_amdgcn_s_setprio(0);
    BAR();

    // phase 3: kk1, i0-3 | stage next U3
    ld4(af, Ac, 8192 + a_off);
    ld4(bf, Bc, 8192 + b_off);
    if (!last) { gl_lds16(pa + 32 + gA, An + 8192 + l_off); gl_lds16(pa + 32 + gA2, An + 8192 + l_off + 4096); }
    BAR(); LGKM0;
    __builtin_amdgcn_s_setprio(1); mfma4x4<0>(acc, af, bf); __builtin_amdgcn_s_setprio(0);
    BAR();

    // phase 4: kk1, i4-7 | stage next U4 | vmcnt: next kk0 resident
    ld4(af, Ac, 8192 + a_off + 2048);
    if (!last) { gl_lds16(pb + 32 + gB, Bn + 8192 + l_off); gl_lds16(pb + 32 + gB2, Bn + 8192 + l_off + 4096); VMCNT4; }
    BAR(); LGKM0;
    __builtin_amdgcn_s_setprio(1); mfma4x4<4>(acc, af, bf); __builtin_amdgcn_s_setprio(0);
    BAR();

    pa += 64; pb += 64; buf ^= 1;
  }
}

// Split (double-f16) NT: C = Ah.Bh^T + Ah.Bl^T + Al.Bh^T, BK=32, 6 phases.
__device__ __forceinline__ void core_split(
    const f16* __restrict__ pah, const f16* __restrict__ pal,
    const f16* __restrict__ pbh, const f16* __restrict__ pbl,
    int K, int lda, int ldb, f16* LDS, f32x4 (&acc)[8][4])
{
  const int tid  = threadIdx.x;
  const int wave = tid >> 6;
  const int lane = tid & 63;
  const int quad = lane >> 4;
  const int col  = lane & 15;
  const int wm = (wave >> 2) * 128;
  const int wn = (wave & 3) * 64;
  const int l_off = wave * 512 + lane * 8;
  const int r0 = wave * 16 + (lane >> 2);
  const int c0 = ((lane & 3) - ((lane >> 3) & 3)) & 3;  // rotation by row>>1
  const long gA  = (long)r0 * lda + c0 * 8;
  const long gA2 = gA + 128L * lda;
  const long gB  = (long)r0 * ldb + c0 * 8;
  const long gB2 = gB + 128L * ldb;
  const int sw = ((quad + ((col >> 1) & 3)) & 3) * 8;
  const int a_off = (wm + col) * 32 + sw;
  const int b_off = (wn + col) * 32 + sw;

  f16* Ah = LDS;
  f16* Al = LDS + 16384;
  f16* Bh = LDS + 32768;
  f16* Bl = LDS + 49152;

  // prologue: tile 0 units U1=Ah U2=Bh U3=Bl U4=Al
  gl_lds16(pah + gA,  Ah + l_off);
  gl_lds16(pah + gA2, Ah + l_off + 4096);
  gl_lds16(pbh + gB,  Bh + l_off);
  gl_lds16(pbh + gB2, Bh + l_off + 4096);
  gl_lds16(pbl + gB,  Bl + l_off);
  gl_lds16(pbl + gB2, Bl + l_off + 4096);
  gl_lds16(pal + gA,  Al + l_off);
  gl_lds16(pal + gA2, Al + l_off + 4096);
  pah += 32; pal += 32; pbh += 32; pbl += 32;
  VMCNT4;
  BAR();

  const int NT = K >> 5;
  int buf = 0;
  for (int t = 0; t < NT; ++t) {
    const int bo = buf * 8192;
    const int bn = (buf ^ 1) * 8192;
    const bool last = (t == NT - 1);
    f16x8 ah[4], ah4[4], bh[4], bl[4], al[4], al4[4];

    // p1: hh i0-3 | stage next Ah
    ld4(ah, Ah + bo, a_off);
    ld4(bh, Bh + bo, b_off);
    if (!last) { gl_lds16(pah + gA, Ah + bn + l_off); gl_lds16(pah + gA2, Ah + bn + l_off + 4096); }
    BAR(); LGKM0;
    __builtin_amdgcn_s_setprio(1); mfma4x4<0>(acc, ah, bh); __builtin_amdgcn_s_setprio(0);
    BAR();

    // p2: hh i4-7 | stage next Bh | vmcnt: cur Bl,Al resident
    ld4(ah4, Ah + bo, a_off + 2048);
    if (!last) { gl_lds16(pbh + gB, Bh + bn + l_off); gl_lds16(pbh + gB2, Bh + bn + l_off + 4096); VMCNT4; }
    else VMCNT0;
    BAR(); LGKM0;
    __builtin_amdgcn_s_setprio(1); mfma4x4<4>(acc, ah4, bh); __builtin_amdgcn_s_setprio(0);
    BAR();

    // p3: h.l i0-3 | stage next Bl
    ld4(bl, Bl + bo, b_off);
    if (!last) { gl_lds16(pbl + gB, Bl + bn + l_off); gl_lds16(pbl + gB2, Bl + bn + l_off + 4096); }
    BAR(); LGKM0;
    __builtin_amdgcn_s_setprio(1); mfma4x4<0>(acc, ah, bl); __builtin_amdgcn_s_setprio(0);
    BAR();

    // p4: h.l i4-7 | stage next Al
    ld4(al, Al + bo, a_off);
    if (!last) { gl_lds16(pal + gA, Al + bn + l_off); gl_lds16(pal + gA2, Al + bn + l_off + 4096); }
    BAR(); LGKM0;
    __builtin_amdgcn_s_setprio(1); mfma4x4<4>(acc, ah4, bl); __builtin_amdgcn_s_setprio(0);
    BAR();

    // p5: l.h i0-3
    ld4(al4, Al + bo, a_off + 2048);
    BAR(); LGKM0;
    __builtin_amdgcn_s_setprio(1); mfma4x4<0>(acc, al, bh); __builtin_amdgcn_s_setprio(0);
    BAR();

    // p6: l.h i4-7 | vmcnt: next Ah,Bh resident
    if (!last) VMCNT4;
    BAR();
    __builtin_amdgcn_s_setprio(1); mfma4x4<4>(acc, al4, bh); __builtin_amdgcn_s_setprio(0);
    BAR();

    pah += 32; pal += 32; pbh += 32; pbl += 32; buf ^= 1;
  }
}

__device__ __forceinline__ void store8_f16(f16* C, long ldc, long tm, long tn,
                                           f32x4 (&acc)[8][4], float scale) {
  const int tid = threadIdx.x, wave = tid >> 6, lane = tid & 63;
  const long cm = tm + (long)((wave >> 2) * 128 + (lane >> 4) * 4);
  const long cn = tn + (long)((wave & 3) * 64 + (lane & 15));
#pragma unroll
  for (int i = 0; i < 8; ++i)
#pragma unroll
    for (int r = 0; r < 4; ++r) {
      const long rowb = (cm + i * 16 + r) * ldc;
#pragma unroll
      for (int j = 0; j < 4; ++j)
        C[rowb + cn + j * 16] = (f16)(acc[i][j][r] * scale);
    }
}

__device__ __forceinline__ void store8_split(f16* Ch, f16* Cl, long ldc, long tm, long tn,
                                             f32x4 (&acc)[8][4]) {
  const int tid = threadIdx.x, wave = tid >> 6, lane = tid & 63;
  const long cm = tm + (long)((wave >> 2) * 128 + (lane >> 4) * 4);
  const long cn = tn + (long)((wave & 3) * 64 + (lane & 15));
#pragma unroll
  for (int i = 0; i < 8; ++i)
#pragma unroll
    for (int r = 0; r < 4; ++r) {
      const long rowb = (cm + i * 16 + r) * ldc;
#pragma unroll
      for (int j = 0; j < 4; ++j) {
        const float v = acc[i][j][r];
        const f16 hi = (f16)v;
        Ch[rowb + cn + j * 16] = hi;
        Cl[rowb + cn + j * 16] = (f16)(v - (float)hi);
      }
    }
}

// Generic plain 256^2 NT-GEMM wrapper (used for the 8-way K-split out-GEMM).
template <int CMODE>
__global__ __launch_bounds__(512, 2) void gemm8p(
    const f16* __restrict__ A, const f16* __restrict__ B, void* __restrict__ C,
    int K, int lda, int ldb, int ldc, int ZB,
    long sA1, long sA2, long sB1, long sB2, long sC1, long sC2, float scale)
{
  __shared__ f16 LDS[65536];
  const int z  = blockIdx.z;
  const int z1 = z % ZB;
  const int z2 = z / ZB;
  const long offA = (long)z1 * sA1 + (long)z2 * sA2;
  const long offB = (long)z1 * sB1 + (long)z2 * sB2;
  const long offC = (long)z1 * sC1 + (long)z2 * sC2;
  const long tm = (long)blockIdx.x * 256;
  const long tn = (long)blockIdx.y * 256;

  f32x4 acc[8][4];
#pragma unroll
  for (int i = 0; i < 8; ++i)
#pragma unroll
    for (int j = 0; j < 4; ++j) acc[i][j] = (f32x4){0.f, 0.f, 0.f, 0.f};

  core_plain(A + offA + tm * lda, B + offB + tn * ldb, K, lda, ldb,
             LDS, LDS + 32768, acc);
  store8_f16((f16*)C + offC, ldc, tm, tn, acc, scale);
}

// ---------------------------------------------------------------------------
// y_vproj (8-phase): blocks [0, G*64): y[slot] = X(split) @ MT[slot]^T
//                    blocks [G*64, +4G*16): vT[hh][b] = WvT[hh] @ Xh[b]^T
// ---------------------------------------------------------------------------
__global__ __launch_bounds__(512, 2) void y_vproj8(
    const f16* __restrict__ Xh, const f16* __restrict__ Xl,
    const f16* __restrict__ MTh, const f16* __restrict__ MTl,
    f16* __restrict__ yh, f16* __restrict__ yl,
    const f16* __restrict__ WvT, f16* __restrict__ vT, int G)
{
  __shared__ f16 LDS[65536];
  const long M1 = 1024 * 1024;
  const int bx = blockIdx.x;
  const int yB = G * 64;

  f32x4 acc[8][4];
#pragma unroll
  for (int i = 0; i < 8; ++i)
#pragma unroll
    for (int j = 0; j < 4; ++j) acc[i][j] = (f32x4){0.f, 0.f, 0.f, 0.f};

  if (bx < yB) {
    const int slot = bx >> 6;
    const int t = bx & 63;
    const long tm = (long)(t & 15) * 256;
    const long tn = (long)(t >> 4) * 256;
    core_split(Xh + tm * 1024, Xl + tm * 1024,
               MTh + (long)slot * M1 + tn * 1024, MTl + (long)slot * M1 + tn * 1024,
               1024, 1024, 1024, LDS, acc);
    store8_split(yh + (long)slot * 4 * M1, yl + (long)slot * 4 * M1, 1024, tm, tn, acc);
  } else {
    const int bx2 = bx - yB;
    const int pair = bx2 >> 4;
    const int hh = pair >> 2, b = pair & 3;
    const int t = bx2 & 15;
    const long tm = (long)(t & 3) * 256;
    const long tn = (long)(t >> 2) * 256;
    core_plain(WvT + (long)hh * M1 + tm * 1024, Xh + (long)b * M1 + tn * 1024,
               1024, 1024, 1024, LDS, LDS + 32768, acc);
    store8_f16(vT + (long)hh * 4 * M1 + (long)b * M1, 1024, tm, tn, acc, 1.0f);
  }
}

// ---------------------------------------------------------------------------
// Fused pipeline dispatch (8-phase): PV of group g + y/vT of group g+1.
// ---------------------------------------------------------------------------
__global__ __launch_bounds__(512, 2) void pv_y_vproj8(
    const f16* __restrict__ Xh, const f16* __restrict__ Xl,
    const f16* __restrict__ MTh, const f16* __restrict__ MTl,
    f16* __restrict__ yh, f16* __restrict__ yl,
    const f16* __restrict__ WvT, f16* __restrict__ vT_w,
    const f16* __restrict__ P, const f16* __restrict__ vT_r,
    f16* __restrict__ h2pv, int G)
{
  __shared__ f16 LDS[65536];
  const long M1 = 1024 * 1024;
  const int bx = blockIdx.x;
  const int yB = G * 64;
  const int vB = 4 * G * 16;

  f32x4 acc[8][4];
#pragma unroll
  for (int i = 0; i < 8; ++i)
#pragma unroll
    for (int j = 0; j < 4; ++j) acc[i][j] = (f32x4){0.f, 0.f, 0.f, 0.f};

  if (bx < yB) {
    const int slot = bx >> 6;
    const int t = bx & 63;
    const long tm = (long)(t & 15) * 256;
    const long tn = (long)(t >> 4) * 256;
    core_split(Xh + tm * 1024, Xl + tm * 1024,
               MTh + (long)slot * M1 + tn * 1024, MTl + (long)slot * M1 + tn * 1024,
               1024, 1024, 1024, LDS, acc);
    store8_split(yh + (long)slot * 4 * M1, yl + (long)slot * 4 * M1, 1024, tm, tn, acc);
  } else if (bx < yB + vB) {
    const int bx2 = bx - yB;
    const int pair = bx2 >> 4;
    const int hh = pair >> 2, b = pair & 3;
    const int t = bx2 & 15;
    const long tm = (long)(t & 3) * 256;
    const long tn = (long)(t >> 2) * 256;
    core_plain(WvT + (long)hh * M1 + tm * 1024, Xh + (long)b * M1 + tn * 1024,
               1024, 1024, 1024, LDS, LDS + 32768, acc);
    store8_f16(vT_w + (long)hh * 4 * M1 + (long)b * M1, 1024, tm, tn, acc, 1.0f);
  } else {
    const int bx2 = bx - yB - vB;
    const int pair = bx2 >> 4;
    const int hh = pair >> 2, b = pair & 3;
    const int t = bx2 & 15;
    const long tm = (long)(t & 3) * 256;
    const long tn = (long)(t >> 2) * 256;
    core_plain(P + (long)hh * 4 * M1 + (long)b * M1 + tm * 1024,
               vT_r + (long)hh * 4 * M1 + (long)b * M1 + tn * 1024,
               1024, 1024, 1024, LDS, LDS + 32768, acc);
    store8_f16(h2pv + (long)b * 1024 * 8192 + (long)hh * 1024, 8192, tm, tn, acc, 1.0f);
  }
}

// out[i] = sum_{z<8} (float)p[z*4M + i]   (fp16 partials -> fp32 out)
__global__ __launch_bounds__(256) void reduce8(const f16* __restrict__ p,
                                               float* __restrict__ out) {
  const long i = ((long)blockIdx.x * 256 + threadIdx.x) * 4;
  const long S = 4L * 1024 * 1024;
  float4 o = {0.f, 0.f, 0.f, 0.f};
#pragma unroll
  for (int z = 0; z < 8; ++z) {
    const f16x4 v = *(const f16x4*)(p + z * S + i);
    o.x += (float)v[0]; o.y += (float)v[1]; o.z += (float)v[2]; o.w += (float)v[3];
  }
  *(float4*)(out + i) = o;
}

// Row softmax over 1024-wide fp32 rows -> fp16 P. One 256-thread block/row.
__global__ __launch_bounds__(256) void softmax_rows(const float* __restrict__ Sc,
                                                    f16* __restrict__ P) {
  const long row = blockIdx.x;
  const int tid = threadIdx.x;
  const float4 v = ((const float4*)(Sc + row * 1024))[tid];
  float m = fmaxf(fmaxf(v.x, v.y), fmaxf(v.z, v.w));
#pragma unroll
  for (int off = 32; off > 0; off >>= 1) m = fmaxf(m, __shfl_xor(m, off, 64));
  __shared__ float red[4], red2[4];
  const int wv = tid >> 6, ln = tid & 63;
  if (ln == 0) red[wv] = m;
  __syncthreads();
  m = fmaxf(fmaxf(red[0], red[1]), fmaxf(red[2], red[3]));
  const float e0 = __expf(v.x - m), e1 = __expf(v.y - m);
  const float e2 = __expf(v.z - m), e3 = __expf(v.w - m);
  float s = e0 + e1 + e2 + e3;
#pragma unroll
  for (int off = 32; off > 0; off >>= 1) s += __shfl_xor(s, off, 64);
  if (ln == 0) red2[wv] = s;
  __syncthreads();
  s = red2[0] + red2[1] + red2[2] + red2[3];
  const float inv = 1.0f / s;
  f16x4 o = {(f16)(e0 * inv), (f16)(e1 * inv), (f16)(e2 * inv), (f16)(e3 * inv)};
  *(f16x4*)(P + row * 1024 + tid * 4) = o;
}

// ---------------------------------------------------------------------------
// One upfront prep dispatch.
// ---------------------------------------------------------------------------
__global__ __launch_bounds__(256) void prep_all(
    const float* __restrict__ X, const float* __restrict__ WQ,
    const float* __restrict__ WK, const float* __restrict__ WV,
    const float* __restrict__ WO,
    f16* __restrict__ Xh, f16* __restrict__ Xl,
    f16* __restrict__ Wqh, f16* __restrict__ Wql,
    f16* __restrict__ Wkh, f16* __restrict__ Wkl,
    f16* __restrict__ WvTa, f16* __restrict__ WoTa)
{
  __shared__ float t[64][65];
  const int bx = blockIdx.x;
  const int tid = threadIdx.x;
  const long M1 = 1024 * 1024;

  if (bx < 20480) {
    const float* src; f16 *hi, *lo; long i;
    if (bx < 4096)       { src = X;  hi = Xh;  lo = Xl;  i = (long)bx * 1024; }
    else if (bx < 12288) { src = WQ; hi = Wqh; lo = Wql; i = (long)(bx - 4096) * 1024; }
    else                 { src = WK; hi = Wkh; lo = Wkl; i = (long)(bx - 12288) * 1024; }
    i += tid * 4;
    const float4 v = *(const float4*)(src + i);
    f16 h0 = (f16)v.x, h1 = (f16)v.y, h2 = (f16)v.z, h3 = (f16)v.w;
    f16x4 oh = {h0, h1, h2, h3};
    f16x4 ol = {(f16)(v.x - (float)h0), (f16)(v.y - (float)h1),
                (f16)(v.z - (float)h2), (f16)(v.w - (float)h3)};
    *(f16x4*)(hi + i) = oh;
    *(f16x4*)(lo + i) = ol;
  } else if (bx < 22528) {
    const int t0 = bx - 20480;
    const int head = t0 >> 8;
    const int tile = t0 & 255;
    const int r0 = (tile & 15) * 64;
    const int c0 = (tile >> 4) * 64;
    const float* in = WV + (long)head * M1;
#pragma unroll
    for (int it = 0; it < 16; ++it) {
      const int idx = it * 256 + tid;
      const int rr = idx >> 6, cc = idx & 63;
      t[rr][cc] = in[(long)(r0 + rr) * 1024 + (c0 + cc)];
    }
    __syncthreads();
#pragma unroll
    for (int it = 0; it < 16; ++it) {
      const int idx = it * 256 + tid;
      const int rr = idx >> 6, cc = idx & 63;
      WvTa[(long)head * M1 + (long)(c0 + rr) * 1024 + (r0 + cc)] = (f16)t[cc][rr];
    }
  } else {
    const int t0 = bx - 22528;
    const int rb = t0 & 127, cb = t0 >> 7;
    const int r0 = rb * 64, c0 = cb * 64;
#pragma unroll
    for (int it = 0; it < 16; ++it) {
      const int idx = it * 256 + tid;
      const int rr = idx >> 6, cc = idx & 63;
      t[rr][cc] = WO[(long)(r0 + rr) * 1024 + (c0 + cc)];
    }
    __syncthreads();
#pragma unroll
    for (int it = 0; it < 16; ++it) {
      const int idx = it * 256 + tid;
      const int rr = idx >> 6, cc = idx & 63;
      WoTa[(long)(c0 + rr) * 8192 + (r0 + cc)] = (f16)t[cc][rr];
    }
  }
}

// ---------------------------------------------------------------------------
// B=4, S=1024, D=1024, H=8.  scores = 32 * X M X^T with M = Wq.Wk^T.
// Double-fp16 score path (absmax 0.0625 verified). G=2 head groups.
// ---------------------------------------------------------------------------
extern "C" void kernel_launch(void* const* d_in, const int* in_sizes, int n_in,
                              void* d_out, int out_size, void* d_ws, size_t ws_size,
                              hipStream_t stream) {
  const float* X  = (const float*)d_in[0];
  const float* WQ = (const float*)d_in[2];
  const float* WK = (const float*)d_in[3];
  const float* WV = (const float*)d_in[4];
  const float* WO = (const float*)d_in[5];
  float* out = (float*)d_out;

  const long M1 = 1024 * 1024;
  const long MB = 1024 * 1024;
  const int G = 2;

  const bool PIPE = ws_size >= (size_t)256 * MB;
  if (ws_size < (size_t)224 * MB) return;  // diagnostic (ws >= 228 MiB known)

  f16* Xh   = (f16*)d_ws;
  f16* Xl   = Xh + 4 * M1;
  f16* MTh  = Xl + 4 * M1;
  f16* MTl  = MTh + 8 * M1;
  f16* h2a  = MTl + 8 * M1;
  f16* WoTa = h2a + 32 * M1;
  f16* WvTa = WoTa + 8 * M1;
  f16* yh   = WvTa + 8 * M1;
  f16* yl   = yh + 8 * M1;
  f16* vTA  = yl + 8 * M1;
  f16* vTB  = PIPE ? vTA + 8 * M1 : vTA;
  float* Sc = (float*)(vTB + 8 * M1);
  f16* P    = PIPE ? (f16*)(Sc + 8 * M1) : yh;
  f16* Wqh = yh;
  f16* Wql = yh + 8 * M1;
  f16* Wkh = yh + 16 * M1;
  f16* Wkl = yh + 24 * M1;
  f16* partials = yh;  // 8 x 4M f16

  prep_all<<<24576, 256, 0, stream>>>(X, WQ, WK, WV, WO,
                                      Xh, Xl, Wqh, Wql, Wkh, Wkl, WvTa, WoTa);
  // MT[h][d2][d1] = sum_e Wk[h][d2][e] * Wq[h][d1][e]
  gemm_nt3<0><<<dim3(8, 8, 8), 256, 0, stream>>>(Wkh, Wkl, Wqh, Wql, MTh, MTl,
                                                 1024, 1024, 8,
                                                 M1, 0, M1, 0, M1, 0, 1.0f);

  if (PIPE) {
    f16* vT_cur = vTA;
    f16* vT_nxt = vTB;
    y_vproj8<<<G * 64 + 4 * G * 16, 512, 0, stream>>>(
        Xh, Xl, MTh, MTl, yh, yl, WvTa, vT_cur, G);
    for (int g = 0; g < 4; ++g) {
      const long h0 = (long)g * G;
      gemm_nt3<1><<<dim3(8, 8, 4 * G), 256, 0, stream>>>(yh, yl, Xh, Xl, Sc, (f16*)0,
                                                         1024, 1024, 4,
                                                         M1, 4 * M1, M1, 0,
                                                         M1, 4 * M1, 32.0f);
      softmax_rows<<<G * 4096, 256, 0, stream>>>(Sc, P);
      if (g < 3) {
        const long h0n = h0 + G;
        pv_y_vproj8<<<G * 64 + 2 * 4 * G * 16, 512, 0, stream>>>(
            Xh, Xl, MTh + h0n * M1, MTl + h0n * M1, yh, yl,
            WvTa + h0n * M1, vT_nxt, P, vT_cur, h2a + h0 * 1024, G);
        f16* tmp = vT_cur; vT_cur = vT_nxt; vT_nxt = tmp;
      } else {
        gemm_nt<0><<<dim3(8, 8, 4 * G), 256, 0, stream>>>(P, vT_cur, h2a + h0 * 1024,
                                                          1024, 1024, 1024, 8192, 4,
                                                          M1, 4 * M1, M1, 4 * M1,
                                                          (long)1024 * 8192, 1024, 1.0f);
      }
    }
  } else {
    for (int g = 0; g < 4; ++g) {
      const long h0 = (long)g * G;
      y_vproj8<<<G * 64 + 4 * G * 16, 512, 0, stream>>>(
          Xh, Xl, MTh + h0 * M1, MTl + h0 * M1, yh, yl, WvTa + h0 * M1, vTA, G);
      gemm_nt3<1><<<dim3(8, 8, 4 * G), 256, 0, stream>>>(yh, yl, Xh, Xl, Sc, (f16*)0,
                                                         1024, 1024, 4,
                                                         M1, 4 * M1, M1, 0,
                                                         M1, 4 * M1, 32.0f);
      softmax_rows<<<G * 4096, 256, 0, stream>>>(Sc, P);
      gemm_nt<0><<<dim3(8, 8, 4 * G), 256, 0, stream>>>(P, vTA, h2a + h0 * 1024,
                                                        1024, 1024, 1024, 8192, 4,
                                                        M1, 4 * M1, M1, 4 * M1,
                                                        (long)1024 * 8192, 1024, 1.0f);
    }
  }

  // 8-way K-split out-GEMM (256^2 8-phase, 512 blocks) + reduce
  gemm8p<0><<<dim3(16, 4, 8), 512, 0, stream>>>(h2a, WoTa, partials,
                                                1024, 8192, 8192, 1024, 8,
                                                1024, 0, 1024, 0, 4 * M1, 0, 1.0f);
  reduce8<<<4096, 256, 0, stream>>>(partials, out);
}